// Round 14
// baseline (67.505 us; speedup 1.0000x reference)
//
#include <hip/hip_runtime.h>
#include <hip/hip_bf16.h>

// Sizes (compile-time)
#define SQ   1024      // S
#define BB   4         // B
#define DM   192       // D_MODEL
#define NH   12        // N_HEAD
#define DH   16        // D_HEAD
#define RL   2048      // RLEN
#define BN   (BB*NH)   // 48

typedef __attribute__((ext_vector_type(8))) short  short8;
typedef __attribute__((ext_vector_type(4))) float  f32x4;
typedef __attribute__((ext_vector_type(2))) float  f32x2;
typedef __attribute__((ext_vector_type(2))) unsigned u32x2;
typedef __attribute__((ext_vector_type(4))) unsigned u32x4;

__device__ __forceinline__ short f2bf(float f) {
    unsigned u = __float_as_uint(f);
    u += 0x7fff + ((u >> 16) & 1);
    return (short)(u >> 16);
}
// pack two f32 -> one u32 of 2 bf16 (lo, hi); compiler emits cvt_pk
__device__ __forceinline__ unsigned pkbf(float lo, float hi) {
    union { __hip_bfloat162 h; unsigned u; } cv;
    cv.h = __float22bfloat162_rn(make_float2(lo, hi));
    return cv.u;
}
__device__ __forceinline__ short8 as_s8(u32x4 v) {
    union { u32x4 u; short8 s; } c; c.u = v; return c.s;
}

// ---------- kernel P: bf16 conversions + weight transposes ----------
__global__ __launch_bounds__(256) void k_prep(
    const float* __restrict__ x, const float* __restrict__ r,
    const float* __restrict__ Wq, const float* __restrict__ Wk,
    const float* __restrict__ Wv, const float* __restrict__ Wr,
    const float* __restrict__ Wo,
    unsigned short* __restrict__ xb, unsigned short* __restrict__ rb,
    unsigned short* __restrict__ WTq, unsigned short* __restrict__ WTk,
    unsigned short* __restrict__ WTv, unsigned short* __restrict__ WTr,
    unsigned short* __restrict__ Wob)
{
    int idx = blockIdx.x * 256 + threadIdx.x;
    if (idx < 786432) { xb[idx] = (unsigned short)f2bf(x[idx]); return; }
    idx -= 786432;
    if (idx < 1572864) { rb[idx] = (unsigned short)f2bf(r[idx]); return; }
    idx -= 1572864;
    if (idx < 36864) { int nd = idx / 192, h = idx % 192;
                       WTq[idx] = (unsigned short)f2bf(Wq[h*192 + nd]); return; }
    idx -= 36864;
    if (idx < 36864) { int nd = idx / 192, h = idx % 192;
                       WTk[idx] = (unsigned short)f2bf(Wk[h*192 + nd]); return; }
    idx -= 36864;
    if (idx < 36864) { int nd = idx / 192, h = idx % 192;
                       WTv[idx] = (unsigned short)f2bf(Wv[h*192 + nd]); return; }
    idx -= 36864;
    if (idx < 36864) { int nd = idx / 192, h = idx % 192;
                       WTr[idx] = (unsigned short)f2bf(Wr[h*192 + nd]); return; }
    idx -= 36864;
    if (idx < 36864) { Wob[idx] = (unsigned short)f2bf(Wo[idx]); return; }
}

// ---------- kernel 1: fused x- and r-projections via MFMA, 2 row-tiles/wave ----------
__global__ __launch_bounds__(256) void k_gemm_xr(
    const unsigned short* __restrict__ xb, const unsigned short* __restrict__ rbm,
    const unsigned short* __restrict__ WTq, const unsigned short* __restrict__ WTk,
    const unsigned short* __restrict__ WTv, const unsigned short* __restrict__ WTr,
    const float* __restrict__ rwb, const float* __restrict__ rrb,
    unsigned short* __restrict__ qwb, unsigned short* __restrict__ qrb,
    unsigned short* __restrict__ kh, unsigned short* __restrict__ vh,
    unsigned short* __restrict__ kr)
{
    int bid = blockIdx.x;
    int tid = threadIdx.x, w = tid >> 6, lane = tid & 63, g = lane >> 4, mm = lane & 15;
    if (bid < 1152) {
        int rt2 = bid / 9, ch = bid % 9;
        int wsel = ch / 3, sub = ch % 3;
        int c0 = sub * 64 + w * 16;
        const unsigned short* WT = (wsel == 0) ? WTq : ((wsel == 1) ? WTk : WTv);
        const unsigned short* arow0 = xb + (size_t)(rt2*32 + mm) * 192 + 8*g;
        const unsigned short* arow1 = arow0 + 16*192;
        const unsigned short* brow = WT + (size_t)(c0 + mm) * 192 + 8*g;
        f32x4 acc0 = {0.f,0.f,0.f,0.f}, acc1 = {0.f,0.f,0.f,0.f};
        #pragma unroll
        for (int kk = 0; kk < 6; ++kk) {
            short8 b  = *(const short8*)(brow  + kk*32);
            short8 a0 = *(const short8*)(arow0 + kk*32);
            short8 a1 = *(const short8*)(arow1 + kk*32);
            acc0 = __builtin_amdgcn_mfma_f32_16x16x32_bf16(a0, b, acc0, 0, 0, 0);
            acc1 = __builtin_amdgcn_mfma_f32_16x16x32_bf16(a1, b, acc1, 0, 0, 0);
        }
        int col = c0 + mm, n = col >> 4, d = col & 15;
        if (wsel == 0) {
            const float SCL = 0.3606737602222409f;   // 0.25 * log2(e)
            float bw = rwb[col], br = rrb[col];
            #pragma unroll
            for (int r = 0; r < 4; ++r) {
                int row = rt2*32 + 4*g + r;
                int i = row >> 2, b2 = row & 3;
                size_t o = ((size_t)(b2*NH + n) * SQ + i) * DH + d;
                qwb[o] = (unsigned short)f2bf((acc0[r] + bw) * SCL);
                qrb[o] = (unsigned short)f2bf((acc0[r] + br) * SCL);
                int row1 = row + 16;
                int i1 = row1 >> 2, b21 = row1 & 3;
                size_t o1 = ((size_t)(b21*NH + n) * SQ + i1) * DH + d;
                qwb[o1] = (unsigned short)f2bf((acc1[r] + bw) * SCL);
                qrb[o1] = (unsigned short)f2bf((acc1[r] + br) * SCL);
            }
        } else {
            unsigned short* dst = (wsel == 1) ? kh : vh;
            #pragma unroll
            for (int r = 0; r < 4; ++r) {
                int row = rt2*32 + 4*g + r;
                int i = row >> 2, b2 = row & 3;
                dst[((size_t)(b2*NH + n) * SQ + i) * DH + d] = (unsigned short)f2bf(acc0[r]);
                int row1 = row + 16;
                int i1 = row1 >> 2, b21 = row1 & 3;
                dst[((size_t)(b21*NH + n) * SQ + i1) * DH + d] = (unsigned short)f2bf(acc1[r]);
            }
        }
    } else {
        int bb = bid - 1152;
        int rt2 = bb / 3, sub = bb % 3;
        int c0 = sub * 64 + w * 16;
        const unsigned short* arow0 = rbm + (size_t)(rt2*32 + mm) * 192 + 8*g;
        const unsigned short* arow1 = arow0 + 16*192;
        const unsigned short* brow = WTr + (size_t)(c0 + mm) * 192 + 8*g;
        f32x4 acc0 = {0.f,0.f,0.f,0.f}, acc1 = {0.f,0.f,0.f,0.f};
        #pragma unroll
        for (int kk = 0; kk < 6; ++kk) {
            short8 b  = *(const short8*)(brow  + kk*32);
            short8 a0 = *(const short8*)(arow0 + kk*32);
            short8 a1 = *(const short8*)(arow1 + kk*32);
            acc0 = __builtin_amdgcn_mfma_f32_16x16x32_bf16(a0, b, acc0, 0, 0, 0);
            acc1 = __builtin_amdgcn_mfma_f32_16x16x32_bf16(a1, b, acc1, 0, 0, 0);
        }
        int col = c0 + mm, n = col >> 4, d = col & 15;
        #pragma unroll
        for (int r = 0; r < 4; ++r) {
            int row = rt2*32 + 4*g + r;
            int j = row >> 2, b2 = row & 3;
            kr[((size_t)(b2*NH + n) * RL + j) * DH + d] = (unsigned short)f2bf(acc0[r]);
            int row1 = row + 16;
            int j1 = row1 >> 2, b21 = row1 & 3;
            kr[((size_t)(b21*NH + n) * RL + j1) * DH + d] = (unsigned short)f2bf(acc1[r]);
        }
    }
}

// ---------- kernel 2: split-K barrier-free attention (r12 body, half keys/block) ----------
// Grid 1536 = 768 (head,qtile) x 2 key-halves -> 6144 waves = 24 waves/CU
// (was 12; r11 counters showed no pipe >50% => latency-bound at low wave count).
// Each block runs chunks t in [8h, 8h+8) and stores UNNORMALIZED partials:
// pO[h][bn][q][d] (f32) and pL[h][bn][q]. k_out_ln combines the two halves.
__global__ __launch_bounds__(256, 3) void k_attn_mfma(
    const unsigned short* __restrict__ qwb, const unsigned short* __restrict__ qrb,
    const unsigned short* __restrict__ kh, const unsigned short* __restrict__ vh,
    const unsigned short* __restrict__ kr,
    float* __restrict__ pO, float* __restrict__ pL)
{
    __shared__ __align__(16) short vbuf[4][2][64*16];  // 16KB: per-wave dbuf V
    __shared__ __align__(16) float bdls[4][16*86];     // 22KB: per-wave BD band [q][c] stride 86

    int bid = blockIdx.x;
    int logical = (bid & 7) * 192 + (bid >> 3);  // XCD swizzle (1536 % 8 == 0)
    int h = logical & 1;                          // key-half
    int l2 = logical >> 1;
    int bn = l2 >> 4;
    int i0b = (l2 & 15) * 64;
    int tid = threadIdx.x, w = tid >> 6, lane = tid & 63;
    int g = lane >> 4, mm = lane & 15;
    size_t headK = (size_t)bn * SQ * DH;
    size_t headR = (size_t)bn * RL * DH;
    int koff = 8 * (g & 1);   // A-frag k-slice (junk for g>=2, multiplied by Q zeros)

    // Q fragments (B-operand: col=mm=query, k=8g+e; zero for g>=2)
    short8 qwf = {0,0,0,0,0,0,0,0}, qrf = {0,0,0,0,0,0,0,0};
    if (g < 2) {
        int qrow = i0b + 16*w + mm;
        qwf = *(const short8*)((const short*)qwb + headK + (size_t)qrow*DH + 8*g);
        qrf = *(const short8*)((const short*)qrb + headK + (size_t)qrow*DH + 8*g);
    }

    const int t0 = 8*h, tEnd = 8*h + 8;
    // ---- prologue: V(t0) -> private LDS; K/KR frags for t0 -> regs ----
    {
        const unsigned short* p = vh + headK + (size_t)(64*t0 + lane)*16;
        u32x4 a0 = *(const u32x4*)p, a1 = *(const u32x4*)(p + 8);
        *(u32x4*)(&vbuf[w][0][lane*16])     = a0;
        *(u32x4*)(&vbuf[w][0][lane*16 + 8]) = a1;
    }
    const int basew0 = 1008 - i0b - 16*w;   // band base; m = basew0+64t+16tau+mm in [0,2047]
    u32x4 ka[4], krg[5], kan[4], krn[5];
    #pragma unroll
    for (int tp = 0; tp < 4; ++tp)
        ka[tp] = *(const u32x4*)(kh + headK + (size_t)(64*t0 + 16*tp + mm)*16 + koff);
    #pragma unroll
    for (int tau = 0; tau < 5; ++tau)
        krg[tau] = *(const u32x4*)(kr + headR + (size_t)(basew0 + 64*t0 + 16*tau + mm)*16 + koff);

    float Lacc = 0.f;
    f32x4 opv = {0.f,0.f,0.f,0.f};
    float* bw_ = &bdls[w][0];
    const f32x4 z = {0.f,0.f,0.f,0.f};

    for (int t = t0; t < tEnd; ++t) {
        int cur = t & 1;
        // 1. issue next-chunk loads early (T14): K/KR frags + own V stage regs
        u32x4 sva = {0,0,0,0}, svb = {0,0,0,0};
        bool ds = (t < tEnd - 1);
        if (ds) {
            #pragma unroll
            for (int tp = 0; tp < 4; ++tp)
                kan[tp] = *(const u32x4*)(kh + headK + (size_t)(64*(t+1) + 16*tp + mm)*16 + koff);
            #pragma unroll
            for (int tau = 0; tau < 5; ++tau)
                krn[tau] = *(const u32x4*)(kr + headR + (size_t)(basew0 + 64*(t+1) + 16*tau + mm)*16 + koff);
            const unsigned short* p = vh + headK + (size_t)(64*(t+1) + lane)*16;
            sva = *(const u32x4*)p; svb = *(const u32x4*)(p + 8);
        }

        // 2. BD band: 5 swapped MFMAs -> private LDS [q][86] via 2x ds_write_b64
        #pragma unroll
        for (int tau = 0; tau < 5; ++tau) {
            f32x4 bd = __builtin_amdgcn_mfma_f32_16x16x32_bf16(as_s8(krg[tau]), qrf, z, 0, 0, 0);
            int wb = mm*86 + 16*tau + 4*g;
            f32x2 lo, hi;
            lo[0] = bd[0]; lo[1] = bd[1];
            hi[0] = bd[2]; hi[1] = bd[3];
            *(f32x2*)(bw_ + wb)     = lo;
            *(f32x2*)(bw_ + wb + 2) = hi;
        }

        // 3. AC (swapped) + shifted-BD add + exp2, all in C-layout
        unsigned pk[8]; float Lc = 0.f;
        #pragma unroll
        for (int tp = 0; tp < 4; ++tp) {
            f32x4 ac = __builtin_amdgcn_mfma_f32_16x16x32_bf16(as_s8(ka[tp]), qwf, z, 0, 0, 0);
            int cb = mm*86 + 16*tp + 4*g + 16 - mm;
            float p0 = __builtin_amdgcn_exp2f(ac[0] + bw_[cb + 0]);
            float p1 = __builtin_amdgcn_exp2f(ac[1] + bw_[cb + 1]);
            float p2 = __builtin_amdgcn_exp2f(ac[2] + bw_[cb + 2]);
            float p3 = __builtin_amdgcn_exp2f(ac[3] + bw_[cb + 3]);
            Lc += (p0 + p1) + (p2 + p3);
            pk[2*tp]     = pkbf(p0, p1);
            pk[2*tp + 1] = pkbf(p2, p3);
        }
        Lacc += Lc;

        // 4. PV with sigma-reordered k-slots (no permlane): slot (g,e) holds
        //    key 16*(e>=4)+4g+(e&3); V tr-reads fetch matching rows.
        unsigned vb0 = (unsigned)(size_t)(&vbuf[w][cur][0])
                     + ((unsigned)mm << 3) + ((unsigned)g << 7);
        {
            u32x2 t0r, t1r;
            asm volatile("ds_read_b64_tr_b16 %0, %2 offset:0\n\t"
                         "ds_read_b64_tr_b16 %1, %2 offset:512\n\t"
                         "s_waitcnt lgkmcnt(0)"
                         : "=&v"(t0r), "=&v"(t1r) : "v"(vb0));
            __builtin_amdgcn_sched_barrier(0);
            union { unsigned u[4]; short8 s; } va, pb;
            va.u[0]=t0r[0]; va.u[1]=t0r[1]; va.u[2]=t1r[0]; va.u[3]=t1r[1];
            pb.u[0]=pk[0]; pb.u[1]=pk[1]; pb.u[2]=pk[2]; pb.u[3]=pk[3];
            opv = __builtin_amdgcn_mfma_f32_16x16x32_bf16(va.s, pb.s, opv, 0, 0, 0);
        }
        {
            u32x2 t0r, t1r;
            asm volatile("ds_read_b64_tr_b16 %0, %2 offset:1024\n\t"
                         "ds_read_b64_tr_b16 %1, %2 offset:1536\n\t"
                         "s_waitcnt lgkmcnt(0)"
                         : "=&v"(t0r), "=&v"(t1r) : "v"(vb0));
            __builtin_amdgcn_sched_barrier(0);
            union { unsigned u[4]; short8 s; } va, pb;
            va.u[0]=t0r[0]; va.u[1]=t0r[1]; va.u[2]=t1r[0]; va.u[3]=t1r[1];
            pb.u[0]=pk[4]; pb.u[1]=pk[5]; pb.u[2]=pk[6]; pb.u[3]=pk[7];
            opv = __builtin_amdgcn_mfma_f32_16x16x32_bf16(va.s, pb.s, opv, 0, 0, 0);
        }

        // 5. own-V stage-write to other buffer; no barrier (within-wave LDS
        //    ordering guaranteed by lgkmcnt inside next chunk's tr-read asm)
        if (ds) {
            *(u32x4*)(&vbuf[w][cur^1][lane*16])     = sva;
            *(u32x4*)(&vbuf[w][cur^1][lane*16 + 8]) = svb;
            #pragma unroll
            for (int tp = 0; tp < 4; ++tp) ka[tp] = kan[tp];
            #pragma unroll
            for (int tau = 0; tau < 5; ++tau) krg[tau] = krn[tau];
        }
    }

    // ---- epilogue: store UNNORMALIZED partials (combine folded into out_ln) ----
    Lacc += __shfl_xor(Lacc, 16);
    Lacc += __shfl_xor(Lacc, 32);
    int i = i0b + 16*w + mm;
    size_t po = ((size_t)(h*48 + bn)*1024 + i)*16 + 4*g;
    *(f32x4*)(pO + po) = opv;
    if (g == 0) pL[(size_t)(h*48 + bn)*1024 + i] = Lacc;
}

// ---------- kernel 3: split-K combine + output projection + residual + LN ----------
// A-fragment built in-register from the two key-half partials:
// a = bf16( (O0+O1) / (L0+L1) ); rest identical to r12's fused out_ln.
__global__ __launch_bounds__(256) void k_out_ln(
    const float* __restrict__ pO, const float* __restrict__ pL,
    const unsigned short* __restrict__ Wob,
    const float* __restrict__ x,
    const float* __restrict__ lnw, const float* __restrict__ lnb,
    float* __restrict__ out)
{
    __shared__ __align__(16) float os[16][196];
    int tid = threadIdx.x, w = tid >> 6, lane = tid & 63, g = lane >> 4, mm = lane & 15;
    int rt = blockIdx.x;
    int R = rt*16 + mm, i = R >> 2, b2 = R & 3;
    short8 a[6];
    #pragma unroll
    for (int kk = 0; kk < 6; ++kk) {
        int nn = 2*kk + (g >> 1);
        int bn = b2*12 + nn;
        size_t base0 = ((size_t)bn*1024 + i)*16 + 8*(g & 1);
        size_t base1 = base0 + (size_t)48*1024*16;
        f32x4 o0a = *(const f32x4*)(pO + base0);
        f32x4 o0b = *(const f32x4*)(pO + base0 + 4);
        f32x4 o1a = *(const f32x4*)(pO + base1);
        f32x4 o1b = *(const f32x4*)(pO + base1 + 4);
        float L = pL[(size_t)bn*1024 + i] + pL[(size_t)(48 + bn)*1024 + i];
        float inv = 1.0f / L;
        union { unsigned u[4]; short8 s; } cv;
        cv.u[0] = pkbf((o0a[0]+o1a[0])*inv, (o0a[1]+o1a[1])*inv);
        cv.u[1] = pkbf((o0a[2]+o1a[2])*inv, (o0a[3]+o1a[3])*inv);
        cv.u[2] = pkbf((o0b[0]+o1b[0])*inv, (o0b[1]+o1b[1])*inv);
        cv.u[3] = pkbf((o0b[2]+o1b[2])*inv, (o0b[3]+o1b[3])*inv);
        a[kk] = cv.s;
    }
    #pragma unroll
    for (int s = 0; s < 3; ++s) {
        int c0 = w*48 + s*16;
        const unsigned short* brow = Wob + (size_t)(c0 + mm)*192 + 8*g;
        f32x4 acc = {0.f,0.f,0.f,0.f};
        #pragma unroll
        for (int kk = 0; kk < 6; ++kk) {
            short8 b = *(const short8*)(brow + kk*32);
            acc = __builtin_amdgcn_mfma_f32_16x16x32_bf16(a[kk], b, acc, 0, 0, 0);
        }
        int col = c0 + mm;
        #pragma unroll
        for (int r = 0; r < 4; ++r) {
            int rl = 4*g + r;
            os[rl][col] = acc[r] + x[(size_t)(rt*16 + rl)*192 + col];
        }
    }
    __syncthreads();
    int row = tid >> 4, seg = tid & 15;
    const float* ors = &os[row][0] + seg*12;
    f32x4 v0 = *(const f32x4*)(ors);
    f32x4 v1 = *(const f32x4*)(ors + 4);
    f32x4 v2 = *(const f32x4*)(ors + 8);
    float s1 = ((v0[0]+v0[1])+(v0[2]+v0[3])) + ((v1[0]+v1[1])+(v1[2]+v1[3]))
             + ((v2[0]+v2[1])+(v2[2]+v2[3]));
    float q1 = ((v0[0]*v0[0]+v0[1]*v0[1])+(v0[2]*v0[2]+v0[3]*v0[3]))
             + ((v1[0]*v1[0]+v1[1]*v1[1])+(v1[2]*v1[2]+v1[3]*v1[3]))
             + ((v2[0]*v2[0]+v2[1]*v2[1])+(v2[2]*v2[2]+v2[3]*v2[3]));
    #pragma unroll
    for (int off = 1; off < 16; off <<= 1) {
        s1 += __shfl_xor(s1, off);
        q1 += __shfl_xor(q1, off);
    }
    float mean = s1 * (1.0f / 192.0f);
    float var  = q1 * (1.0f / 192.0f) - mean * mean;
    float rstd = rsqrtf(var + 1e-12f);
    int c0 = seg * 12;
    size_t ro = (size_t)(rt*16 + row) * 192;
    #pragma unroll
    for (int c = 0; c < 12; ++c) {
        float v = (c < 4) ? v0[c] : ((c < 8) ? v1[c-4] : v2[c-8]);
        out[ro + c0 + c] = (v - mean) * rstd * lnw[c0 + c] + lnb[c0 + c];
    }
}

extern "C" void kernel_launch(void* const* d_in, const int* in_sizes, int n_in,
                              void* d_out, int out_size, void* d_ws, size_t ws_size,
                              hipStream_t stream) {
    const float* x   = (const float*)d_in[0];
    const float* r   = (const float*)d_in[1];
    // d_in[2] = mask0, zeroed by reference -> ignored
    const float* Wq  = (const float*)d_in[3];
    const float* Wk  = (const float*)d_in[4];
    const float* Wv  = (const float*)d_in[5];
    const float* Wo  = (const float*)d_in[6];
    const float* Wr  = (const float*)d_in[7];
    const float* rwb = (const float*)d_in[8];
    const float* rrb = (const float*)d_in[9];
    const float* lnw = (const float*)d_in[10];
    const float* lnb = (const float*)d_in[11];
    float* out = (float*)d_out;

    // workspace layout (bytes). pO/pL intentionally OVERLAY xb/rb (dead after
    // k_gemm_xr); WT*/Wob live outside the overlay (needed by k_out_ln).
    char* ws = (char*)d_ws;
    unsigned short* qwb = (unsigned short*)(ws + 0);         // [48][1024][16] bf16
    unsigned short* qrb = (unsigned short*)(ws + 1572864);
    unsigned short* kh  = (unsigned short*)(ws + 3145728);
    unsigned short* vh  = (unsigned short*)(ws + 4718592);
    unsigned short* kr  = (unsigned short*)(ws + 6291456);   // [48][2048][16] bf16, ends 9437184
    unsigned short* WTq = (unsigned short*)(ws + 9437184);   // [192][192] bf16 (T)
    unsigned short* WTk = (unsigned short*)(ws + 9510912);
    unsigned short* WTv = (unsigned short*)(ws + 9584640);
    unsigned short* WTr = (unsigned short*)(ws + 9658368);
    unsigned short* Wob = (unsigned short*)(ws + 9732096);   // ends 9805824
    unsigned short* xb  = (unsigned short*)(ws + 9805824);   // [4096][192] bf16, ends 11378688
    unsigned short* rb  = (unsigned short*)(ws + 11378688);  // [8192][192] bf16, ends 14524416
    float*          pO  = (float*)(ws + 9805824);            // [2][48][1024][16] f32 (overlays xb/rb), ends 16097280
    float*          pL  = (float*)(ws + 16097280);           // [2][48][1024] f32, ends 16490496

    k_prep<<<dim3(9936), dim3(256), 0, stream>>>(x, r, Wq, Wk, Wv, Wr, Wo,
                                                 xb, rb, WTq, WTk, WTv, WTr, Wob);
    k_gemm_xr<<<dim3(1920), dim3(256), 0, stream>>>(xb, rb, WTq, WTk, WTv, WTr,
                                                    rwb, rrb, qwb, qrb, kh, vh, kr);
    k_attn_mfma<<<dim3(1536), dim3(256), 0, stream>>>(qwb, qrb, kh, vh, kr, pO, pL);
    k_out_ln<<<dim3(256), dim3(256), 0, stream>>>(pO, pL, Wob, x, lnw, lnb, out);
}

// Round 15
// 60.657 us; speedup vs baseline: 1.1129x; 1.1129x over previous
//
#include <hip/hip_runtime.h>
#include <hip/hip_bf16.h>

// Sizes (compile-time)
#define SQ   1024      // S
#define BB   4         // B
#define DM   192       // D_MODEL
#define NH   12        // N_HEAD
#define DH   16        // D_HEAD
#define RL   2048      // RLEN
#define BN   (BB*NH)   // 48

typedef __attribute__((ext_vector_type(8))) short  short8;
typedef __attribute__((ext_vector_type(4))) float  f32x4;
typedef __attribute__((ext_vector_type(2))) float  f32x2;
typedef __attribute__((ext_vector_type(2))) unsigned u32x2;
typedef __attribute__((ext_vector_type(4))) unsigned u32x4;

__device__ __forceinline__ short f2bf(float f) {
    unsigned u = __float_as_uint(f);
    u += 0x7fff + ((u >> 16) & 1);
    return (short)(u >> 16);
}
// pack two f32 -> one u32 of 2 bf16 (lo, hi); compiler emits cvt_pk (RNE)
__device__ __forceinline__ unsigned pkbf(float lo, float hi) {
    union { __hip_bfloat162 h; unsigned u; } cv;
    cv.h = __float22bfloat162_rn(make_float2(lo, hi));
    return cv.u;
}
__device__ __forceinline__ short8 as_s8(u32x4 v) {
    union { u32x4 u; short8 s; } c; c.u = v; return c.s;
}

// ---------- kernel P: bf16 conversions + weight transposes (4x vectorized) ----------
// unit = 4 elements. xb 196608u | rb 393216u | WTq/WTk/WTv/WTr 9216u each | Wob 9216u
// grid 2484 x 256 = 635904 units exactly.
__global__ __launch_bounds__(256) void k_prep(
    const float* __restrict__ x, const float* __restrict__ r,
    const float* __restrict__ Wq, const float* __restrict__ Wk,
    const float* __restrict__ Wv, const float* __restrict__ Wr,
    const float* __restrict__ Wo,
    unsigned short* __restrict__ xb, unsigned short* __restrict__ rb,
    unsigned short* __restrict__ WTq, unsigned short* __restrict__ WTk,
    unsigned short* __restrict__ WTv, unsigned short* __restrict__ WTr,
    unsigned short* __restrict__ Wob)
{
    int u = blockIdx.x * 256 + threadIdx.x;
    if (u < 196608) {
        f32x4 v = *(const f32x4*)(x + (size_t)u*4);
        u32x2 o = { pkbf(v[0], v[1]), pkbf(v[2], v[3]) };
        *(u32x2*)(xb + (size_t)u*4) = o;
        return;
    }
    u -= 196608;
    if (u < 393216) {
        f32x4 v = *(const f32x4*)(r + (size_t)u*4);
        u32x2 o = { pkbf(v[0], v[1]), pkbf(v[2], v[3]) };
        *(u32x2*)(rb + (size_t)u*4) = o;
        return;
    }
    u -= 393216;
    if (u < 4*9216) {
        int sel = u / 9216, uu = u % 9216;
        const float* W = (sel == 0) ? Wq : ((sel == 1) ? Wk : ((sel == 2) ? Wv : Wr));
        unsigned short* WT = (sel == 0) ? WTq : ((sel == 1) ? WTk : ((sel == 2) ? WTv : WTr));
        int nd = uu / 48, h0 = (uu % 48) * 4;     // WT[nd][h0..h0+3] = W[h][nd]
        float v0 = W[(size_t)(h0+0)*192 + nd];
        float v1 = W[(size_t)(h0+1)*192 + nd];
        float v2 = W[(size_t)(h0+2)*192 + nd];
        float v3 = W[(size_t)(h0+3)*192 + nd];
        u32x2 o = { pkbf(v0, v1), pkbf(v2, v3) };
        *(u32x2*)(WT + (size_t)uu*4) = o;
        return;
    }
    u -= 4*9216;
    if (u < 9216) {
        f32x4 v = *(const f32x4*)(Wo + (size_t)u*4);
        u32x2 o = { pkbf(v[0], v[1]), pkbf(v[2], v[3]) };
        *(u32x2*)(Wob + (size_t)u*4) = o;
    }
}

// ---------- kernel 1: fused x- and r-projections via MFMA, 2 row-tiles/wave ----------
__global__ __launch_bounds__(256) void k_gemm_xr(
    const unsigned short* __restrict__ xb, const unsigned short* __restrict__ rbm,
    const unsigned short* __restrict__ WTq, const unsigned short* __restrict__ WTk,
    const unsigned short* __restrict__ WTv, const unsigned short* __restrict__ WTr,
    const float* __restrict__ rwb, const float* __restrict__ rrb,
    unsigned short* __restrict__ qwb, unsigned short* __restrict__ qrb,
    unsigned short* __restrict__ kh, unsigned short* __restrict__ vh,
    unsigned short* __restrict__ kr)
{
    int bid = blockIdx.x;
    int tid = threadIdx.x, w = tid >> 6, lane = tid & 63, g = lane >> 4, mm = lane & 15;
    if (bid < 1152) {
        int rt2 = bid / 9, ch = bid % 9;
        int wsel = ch / 3, sub = ch % 3;
        int c0 = sub * 64 + w * 16;
        const unsigned short* WT = (wsel == 0) ? WTq : ((wsel == 1) ? WTk : WTv);
        const unsigned short* arow0 = xb + (size_t)(rt2*32 + mm) * 192 + 8*g;
        const unsigned short* arow1 = arow0 + 16*192;
        const unsigned short* brow = WT + (size_t)(c0 + mm) * 192 + 8*g;
        f32x4 acc0 = {0.f,0.f,0.f,0.f}, acc1 = {0.f,0.f,0.f,0.f};
        #pragma unroll
        for (int kk = 0; kk < 6; ++kk) {
            short8 b  = *(const short8*)(brow  + kk*32);
            short8 a0 = *(const short8*)(arow0 + kk*32);
            short8 a1 = *(const short8*)(arow1 + kk*32);
            acc0 = __builtin_amdgcn_mfma_f32_16x16x32_bf16(a0, b, acc0, 0, 0, 0);
            acc1 = __builtin_amdgcn_mfma_f32_16x16x32_bf16(a1, b, acc1, 0, 0, 0);
        }
        int col = c0 + mm, n = col >> 4, d = col & 15;
        if (wsel == 0) {
            const float SCL = 0.3606737602222409f;   // 0.25 * log2(e)
            float bw = rwb[col], br = rrb[col];
            #pragma unroll
            for (int r = 0; r < 4; ++r) {
                int row = rt2*32 + 4*g + r;
                int i = row >> 2, b2 = row & 3;
                size_t o = ((size_t)(b2*NH + n) * SQ + i) * DH + d;
                qwb[o] = (unsigned short)f2bf((acc0[r] + bw) * SCL);
                qrb[o] = (unsigned short)f2bf((acc0[r] + br) * SCL);
                int row1 = row + 16;
                int i1 = row1 >> 2, b21 = row1 & 3;
                size_t o1 = ((size_t)(b21*NH + n) * SQ + i1) * DH + d;
                qwb[o1] = (unsigned short)f2bf((acc1[r] + bw) * SCL);
                qrb[o1] = (unsigned short)f2bf((acc1[r] + br) * SCL);
            }
        } else {
            unsigned short* dst = (wsel == 1) ? kh : vh;
            #pragma unroll
            for (int r = 0; r < 4; ++r) {
                int row = rt2*32 + 4*g + r;
                int i = row >> 2, b2 = row & 3;
                dst[((size_t)(b2*NH + n) * SQ + i) * DH + d] = (unsigned short)f2bf(acc0[r]);
                int row1 = row + 16;
                int i1 = row1 >> 2, b21 = row1 & 3;
                dst[((size_t)(b21*NH + n) * SQ + i1) * DH + d] = (unsigned short)f2bf(acc1[r]);
            }
        }
    } else {
        int bb = bid - 1152;
        int rt2 = bb / 3, sub = bb % 3;
        int c0 = sub * 64 + w * 16;
        const unsigned short* arow0 = rbm + (size_t)(rt2*32 + mm) * 192 + 8*g;
        const unsigned short* arow1 = arow0 + 16*192;
        const unsigned short* brow = WTr + (size_t)(c0 + mm) * 192 + 8*g;
        f32x4 acc0 = {0.f,0.f,0.f,0.f}, acc1 = {0.f,0.f,0.f,0.f};
        #pragma unroll
        for (int kk = 0; kk < 6; ++kk) {
            short8 b  = *(const short8*)(brow  + kk*32);
            short8 a0 = *(const short8*)(arow0 + kk*32);
            short8 a1 = *(const short8*)(arow1 + kk*32);
            acc0 = __builtin_amdgcn_mfma_f32_16x16x32_bf16(a0, b, acc0, 0, 0, 0);
            acc1 = __builtin_amdgcn_mfma_f32_16x16x32_bf16(a1, b, acc1, 0, 0, 0);
        }
        int col = c0 + mm, n = col >> 4, d = col & 15;
        #pragma unroll
        for (int r = 0; r < 4; ++r) {
            int row = rt2*32 + 4*g + r;
            int j = row >> 2, b2 = row & 3;
            kr[((size_t)(b2*NH + n) * RL + j) * DH + d] = (unsigned short)f2bf(acc0[r]);
            int row1 = row + 16;
            int j1 = row1 >> 2, b21 = row1 & 3;
            kr[((size_t)(b21*NH + n) * RL + j1) * DH + d] = (unsigned short)f2bf(acc1[r]);
        }
    }
}

// ---------- kernel 2: barrier-free swapped-layout MFMA flash attention ----------
// r12 champion, byte-for-byte: conflict-free band writes (stride 86, 2x b64),
// sigma-reordered PV k-slots (no permlane), per-wave private V dbuf, 0 barriers.
__global__ __launch_bounds__(256, 3) void k_attn_mfma(
    const unsigned short* __restrict__ qwb, const unsigned short* __restrict__ qrb,
    const unsigned short* __restrict__ kh, const unsigned short* __restrict__ vh,
    const unsigned short* __restrict__ kr, unsigned short* __restrict__ av_b)
{
    __shared__ __align__(16) short vbuf[4][2][64*16];  // 16KB: per-wave dbuf V
    __shared__ __align__(16) float bdls[4][16*86];     // 22KB: per-wave BD band [q][c] stride 86

    int bid = blockIdx.x;
    int logical = (bid & 7) * 96 + (bid >> 3);  // XCD swizzle (768 % 8 == 0)
    int bn = logical >> 4;
    int i0b = (logical & 15) * 64;
    int tid = threadIdx.x, w = tid >> 6, lane = tid & 63;
    int g = lane >> 4, mm = lane & 15;
    size_t headK = (size_t)bn * SQ * DH;
    size_t headR = (size_t)bn * RL * DH;
    int koff = 8 * (g & 1);   // A-frag k-slice (junk for g>=2, multiplied by Q zeros)

    // Q fragments (B-operand: col=mm=query, k=8g+e; zero for g>=2)
    short8 qwf = {0,0,0,0,0,0,0,0}, qrf = {0,0,0,0,0,0,0,0};
    if (g < 2) {
        int qrow = i0b + 16*w + mm;
        qwf = *(const short8*)((const short*)qwb + headK + (size_t)qrow*DH + 8*g);
        qrf = *(const short8*)((const short*)qrb + headK + (size_t)qrow*DH + 8*g);
    }

    // ---- prologue: V0 -> private LDS; K0/KR0 fragments -> regs (no barrier) ----
    {
        const unsigned short* p = vh + headK + (size_t)lane*16;
        u32x4 a0 = *(const u32x4*)p, a1 = *(const u32x4*)(p + 8);
        *(u32x4*)(&vbuf[w][0][lane*16])     = a0;
        *(u32x4*)(&vbuf[w][0][lane*16 + 8]) = a1;
    }
    const int basew0 = 1008 - i0b - 16*w;   // band base; m = basew0+64t+16tau+mm in [0,2047]
    u32x4 ka[4], krg[5], kan[4], krn[5];
    #pragma unroll
    for (int tp = 0; tp < 4; ++tp)
        ka[tp] = *(const u32x4*)(kh + headK + (size_t)(16*tp + mm)*16 + koff);
    #pragma unroll
    for (int tau = 0; tau < 5; ++tau)
        krg[tau] = *(const u32x4*)(kr + headR + (size_t)(basew0 + 16*tau + mm)*16 + koff);

    float Lacc = 0.f;
    f32x4 opv = {0.f,0.f,0.f,0.f};
    float* bw_ = &bdls[w][0];
    const f32x4 z = {0.f,0.f,0.f,0.f};

    for (int t = 0; t < 16; ++t) {
        int cur = t & 1;
        // 1. issue next-chunk loads early (T14): K/KR frags + own V stage regs
        u32x4 sva = {0,0,0,0}, svb = {0,0,0,0};
        bool ds = (t < 15);
        if (ds) {
            #pragma unroll
            for (int tp = 0; tp < 4; ++tp)
                kan[tp] = *(const u32x4*)(kh + headK + (size_t)(64*(t+1) + 16*tp + mm)*16 + koff);
            #pragma unroll
            for (int tau = 0; tau < 5; ++tau)
                krn[tau] = *(const u32x4*)(kr + headR + (size_t)(basew0 + 64*(t+1) + 16*tau + mm)*16 + koff);
            const unsigned short* p = vh + headK + (size_t)(64*(t+1) + lane)*16;
            sva = *(const u32x4*)p; svb = *(const u32x4*)(p + 8);
        }

        // 2. BD band: 5 swapped MFMAs -> private LDS [q][86] via 2x ds_write_b64
        //    (banks 22mm+4g: distinct over mm => conflict-free)
        #pragma unroll
        for (int tau = 0; tau < 5; ++tau) {
            f32x4 bd = __builtin_amdgcn_mfma_f32_16x16x32_bf16(as_s8(krg[tau]), qrf, z, 0, 0, 0);
            int wb = mm*86 + 16*tau + 4*g;
            f32x2 lo, hi;
            lo[0] = bd[0]; lo[1] = bd[1];
            hi[0] = bd[2]; hi[1] = bd[3];
            *(f32x2*)(bw_ + wb)     = lo;
            *(f32x2*)(bw_ + wb + 2) = hi;
        }

        // 3. AC (swapped) + shifted-BD add + exp2, all in C-layout
        unsigned pk[8]; float Lc = 0.f;
        #pragma unroll
        for (int tp = 0; tp < 4; ++tp) {
            f32x4 ac = __builtin_amdgcn_mfma_f32_16x16x32_bf16(as_s8(ka[tp]), qwf, z, 0, 0, 0);
            int cb = mm*86 + 16*tp + 4*g + 16 - mm;
            float p0 = __builtin_amdgcn_exp2f(ac[0] + bw_[cb + 0]);
            float p1 = __builtin_amdgcn_exp2f(ac[1] + bw_[cb + 1]);
            float p2 = __builtin_amdgcn_exp2f(ac[2] + bw_[cb + 2]);
            float p3 = __builtin_amdgcn_exp2f(ac[3] + bw_[cb + 3]);
            Lc += (p0 + p1) + (p2 + p3);
            pk[2*tp]     = pkbf(p0, p1);
            pk[2*tp + 1] = pkbf(p2, p3);
        }
        Lacc += Lc;

        // 4. PV with sigma-reordered k-slots: slot (g,e) holds key
        //    16*(e>=4)+4g+(e&3). pk[] feeds the B-frag directly (no permlane);
        //    V tr-reads fetch matching key rows: block g (keys 4g..4g+3) at
        //    offset 0, block g+4 at 512, g+8 at 1024, g+12 at 1536.
        unsigned vb0 = (unsigned)(size_t)(&vbuf[w][cur][0])
                     + ((unsigned)mm << 3) + ((unsigned)g << 7);
        {
            u32x2 t0, t1;
            asm volatile("ds_read_b64_tr_b16 %0, %2 offset:0\n\t"
                         "ds_read_b64_tr_b16 %1, %2 offset:512\n\t"
                         "s_waitcnt lgkmcnt(0)"
                         : "=&v"(t0), "=&v"(t1) : "v"(vb0));
            __builtin_amdgcn_sched_barrier(0);
            union { unsigned u[4]; short8 s; } va, pb;
            va.u[0]=t0[0]; va.u[1]=t0[1]; va.u[2]=t1[0]; va.u[3]=t1[1];
            pb.u[0]=pk[0]; pb.u[1]=pk[1]; pb.u[2]=pk[2]; pb.u[3]=pk[3];
            opv = __builtin_amdgcn_mfma_f32_16x16x32_bf16(va.s, pb.s, opv, 0, 0, 0);
        }
        {
            u32x2 t0, t1;
            asm volatile("ds_read_b64_tr_b16 %0, %2 offset:1024\n\t"
                         "ds_read_b64_tr_b16 %1, %2 offset:1536\n\t"
                         "s_waitcnt lgkmcnt(0)"
                         : "=&v"(t0), "=&v"(t1) : "v"(vb0));
            __builtin_amdgcn_sched_barrier(0);
            union { unsigned u[4]; short8 s; } va, pb;
            va.u[0]=t0[0]; va.u[1]=t0[1]; va.u[2]=t1[0]; va.u[3]=t1[1];
            pb.u[0]=pk[4]; pb.u[1]=pk[5]; pb.u[2]=pk[6]; pb.u[3]=pk[7];
            opv = __builtin_amdgcn_mfma_f32_16x16x32_bf16(va.s, pb.s, opv, 0, 0, 0);
        }

        // 5. own-V stage-write to other buffer; no barrier (within-wave LDS
        //    ordering guaranteed by lgkmcnt inside next chunk's tr-read asm)
        if (ds) {
            *(u32x4*)(&vbuf[w][cur^1][lane*16])     = sva;
            *(u32x4*)(&vbuf[w][cur^1][lane*16 + 8]) = svb;
            #pragma unroll
            for (int tp = 0; tp < 4; ++tp) ka[tp] = kan[tp];
            #pragma unroll
            for (int tau = 0; tau < 5; ++tau) krg[tau] = krn[tau];
        }
    }

    // ---- epilogue: L is lane-local per query; reduce across g, store bf16 ----
    Lacc += __shfl_xor(Lacc, 16);
    Lacc += __shfl_xor(Lacc, 32);
    float inv = 1.0f / Lacc;
    int b2 = bn / NH, nn = bn % NH;
    int i = i0b + 16*w + mm;
    unsigned o0 = pkbf(opv[0]*inv, opv[1]*inv);
    unsigned o1 = pkbf(opv[2]*inv, opv[3]*inv);
    u32x2 ov = {o0, o1};
    *(u32x2*)(av_b + ((size_t)i*4 + b2)*192 + nn*16 + 4*g) = ov;
}

// ---------- kernel 3: output projection + residual + LayerNorm (fused) ----------
__global__ __launch_bounds__(256) void k_out_ln(
    const unsigned short* __restrict__ avb, const unsigned short* __restrict__ Wob,
    const float* __restrict__ x,
    const float* __restrict__ lnw, const float* __restrict__ lnb,
    float* __restrict__ out)
{
    __shared__ __align__(16) float os[16][196];
    int tid = threadIdx.x, w = tid >> 6, lane = tid & 63, g = lane >> 4, mm = lane & 15;
    int rt = blockIdx.x;
    const unsigned short* arow = avb + (size_t)(rt*16 + mm)*192 + 8*g;
    short8 a[6];
    #pragma unroll
    for (int kk = 0; kk < 6; ++kk) a[kk] = *(const short8*)(arow + kk*32);
    #pragma unroll
    for (int s = 0; s < 3; ++s) {
        int c0 = w*48 + s*16;
        const unsigned short* brow = Wob + (size_t)(c0 + mm)*192 + 8*g;
        f32x4 acc = {0.f,0.f,0.f,0.f};
        #pragma unroll
        for (int kk = 0; kk < 6; ++kk) {
            short8 b = *(const short8*)(brow + kk*32);
            acc = __builtin_amdgcn_mfma_f32_16x16x32_bf16(a[kk], b, acc, 0, 0, 0);
        }
        int col = c0 + mm;
        #pragma unroll
        for (int r = 0; r < 4; ++r) {
            int rl = 4*g + r;
            os[rl][col] = acc[r] + x[(size_t)(rt*16 + rl)*192 + col];
        }
    }
    __syncthreads();
    int row = tid >> 4, seg = tid & 15;
    const float* ors = &os[row][0] + seg*12;
    f32x4 v0 = *(const f32x4*)(ors);
    f32x4 v1 = *(const f32x4*)(ors + 4);
    f32x4 v2 = *(const f32x4*)(ors + 8);
    float s1 = ((v0[0]+v0[1])+(v0[2]+v0[3])) + ((v1[0]+v1[1])+(v1[2]+v1[3]))
             + ((v2[0]+v2[1])+(v2[2]+v2[3]));
    float q1 = ((v0[0]*v0[0]+v0[1]*v0[1])+(v0[2]*v0[2]+v0[3]*v0[3]))
             + ((v1[0]*v1[0]+v1[1]*v1[1])+(v1[2]*v1[2]+v1[3]*v1[3]))
             + ((v2[0]*v2[0]+v2[1]*v2[1])+(v2[2]*v2[2]+v2[3]*v2[3]));
    #pragma unroll
    for (int off = 1; off < 16; off <<= 1) {
        s1 += __shfl_xor(s1, off);
        q1 += __shfl_xor(q1, off);
    }
    float mean = s1 * (1.0f / 192.0f);
    float var  = q1 * (1.0f / 192.0f) - mean * mean;
    float rstd = rsqrtf(var + 1e-12f);
    int c0 = seg * 12;
    size_t ro = (size_t)(rt*16 + row) * 192;
    #pragma unroll
    for (int c = 0; c < 12; ++c) {
        float v = (c < 4) ? v0[c] : ((c < 8) ? v1[c-4] : v2[c-8]);
        out[ro + c0 + c] = (v - mean) * rstd * lnw[c0 + c] + lnb[c0 + c];
    }
}

extern "C" void kernel_launch(void* const* d_in, const int* in_sizes, int n_in,
                              void* d_out, int out_size, void* d_ws, size_t ws_size,
                              hipStream_t stream) {
    const float* x   = (const float*)d_in[0];
    const float* r   = (const float*)d_in[1];
    // d_in[2] = mask0, zeroed by reference -> ignored
    const float* Wq  = (const float*)d_in[3];
    const float* Wk  = (const float*)d_in[4];
    const float* Wv  = (const float*)d_in[5];
    const float* Wo  = (const float*)d_in[6];
    const float* Wr  = (const float*)d_in[7];
    const float* rwb = (const float*)d_in[8];
    const float* rrb = (const float*)d_in[9];
    const float* lnw = (const float*)d_in[10];
    const float* lnb = (const float*)d_in[11];
    float* out = (float*)d_out;

    char* ws = (char*)d_ws;
    unsigned short* qwb = (unsigned short*)(ws + 0);         // [48][1024][16] bf16
    unsigned short* qrb = (unsigned short*)(ws + 1572864);
    unsigned short* kh  = (unsigned short*)(ws + 3145728);
    unsigned short* vh  = (unsigned short*)(ws + 4718592);
    unsigned short* kr  = (unsigned short*)(ws + 6291456);   // [48][2048][16] bf16
    unsigned short* avb = (unsigned short*)(ws + 9437184);   // [4096][192] bf16
    unsigned short* xb  = (unsigned short*)(ws + 11010048);  // [4096][192] bf16
    unsigned short* rb  = (unsigned short*)(ws + 12582912);  // [8192][192] bf16
    unsigned short* WTq = (unsigned short*)(ws + 15728640);  // [192][192] bf16 (T)
    unsigned short* WTk = (unsigned short*)(ws + 15802368);
    unsigned short* WTv = (unsigned short*)(ws + 15876096);
    unsigned short* WTr = (unsigned short*)(ws + 15949824);
    unsigned short* Wob = (unsigned short*)(ws + 16023552);  // [192][192] bf16

    k_prep<<<dim3(2484), dim3(256), 0, stream>>>(x, r, Wq, Wk, Wv, Wr, Wo,
                                                 xb, rb, WTq, WTk, WTv, WTr, Wob);
    k_gemm_xr<<<dim3(1920), dim3(256), 0, stream>>>(xb, rb, WTq, WTk, WTv, WTr,
                                                    rwb, rrb, qwb, qrb, kh, vh, kr);
    k_attn_mfma<<<dim3(768), dim3(256), 0, stream>>>(qwb, qrb, kh, vh, kr, avb);
    k_out_ln<<<dim3(256), dim3(256), 0, stream>>>(avb, Wob, x, lnw, lnb, out);
}